// Round 5
// baseline (182.414 us; speedup 1.0000x reference)
//
#include <hip/hip_runtime.h>

#define SCALE 0.17677669529663687f  // 1/sqrt(32)
#define PSTR 513                    // padded s_p row stride (bank spread)

// ---------------------------------------------------------------------------
// Single fused kernel: one block per query row i. 512 blocks x 512 thr.
//
// Prologue (per block, recomputed): q_s = (x[i]@Wq)*SCALE;
//   qce[c,h] = sum_d q_s[h*32+d]*We[c*256+h*32+d]
//   qcx[c,h] = sum_d q_s[h*32+d]*Wk[c*256+h*32+d]
// P1: logit[h][j] = sum_c e[i,j,c]*qce[c,h] + sum_c x[j,c]*qcx[c,h]
// P2: softmax over j per head
// P3: ae[h,c] = sum_j p[h,j]*e[i,j,c];  px[h,c] = sum_j p[h,j]*x[j,c]
// Epilogue: emb[nd] = sum_c ae[n,c]We[c,nd] + px[n,c]Wv[c,nd]; out = emb@Wo+bo
// ---------------------------------------------------------------------------
__global__ __launch_bounds__(512, 4) void fused_kernel(
    const float* __restrict__ e, const float* __restrict__ x,
    const float* __restrict__ Wq, const float* __restrict__ Wk,
    const float* __restrict__ We, const float* __restrict__ Wv,
    const float* __restrict__ Wo, const float* __restrict__ bo,
    float* __restrict__ out) {
  const int t = threadIdx.x, i = blockIdx.x;
  __shared__ float s_x[64];
  __shared__ __align__(16) float s_q[256];
  __shared__ __align__(16) float s_qc[1024];       //  4 KB coefs [c*16 + (h | 8+h)]
  __shared__ __align__(16) float s_p[8 * PSTR];    // ~16 KB probs, padded stride
  __shared__ __align__(16) float s_part[8 * 1024]; // 32 KB wave partials (ae|px)
  __shared__ float s_ae[512], s_px[512];
  __shared__ float s_emb[256];
  __shared__ float s_op[8 * 64];

  // ---- Prologue: coefficients
  if (t < 64) s_x[t] = x[i * 64 + t];
  __syncthreads();
  if (t < 256) {
    float a = 0;
#pragma unroll 8
    for (int c = 0; c < 64; ++c) a += s_x[c] * Wq[c * 256 + t];
    s_q[t] = a * SCALE;
  }
  __syncthreads();
  {
    const int c = t >> 3, h = t & 7;
    const float4* wer = (const float4*)(We + c * 256 + h * 32);
    const float4* wkr = (const float4*)(Wk + c * 256 + h * 32);
    const float4* qr = (const float4*)(s_q + h * 32);
    float se = 0, sk = 0;
#pragma unroll
    for (int u = 0; u < 8; ++u) {
      float4 w1 = wer[u], w2 = wkr[u], qv = qr[u];
      se += qv.x * w1.x + qv.y * w1.y + qv.z * w1.z + qv.w * w1.w;
      sk += qv.x * w2.x + qv.y * w2.y + qv.z * w2.z + qv.w * w2.w;
    }
    s_qc[c * 16 + h] = se;
    s_qc[c * 16 + 8 + h] = sk;
  }
  __syncthreads();

  const int c4 = t & 15;       // c-quad lane
  const int strip = t >> 4;    // 0..31, 16 j each
  const float4* e4 = (const float4*)(e + (size_t)i * 512 * 64);  // [j][16]
  const float4* x4 = (const float4*)x;                           // [j][16]

  // hoist this thread's 64 coefficients into registers
  float ce[4][8], cx[4][8];
#pragma unroll
  for (int cc = 0; cc < 4; ++cc) {
    const int cb = (c4 * 4 + cc) * 16;
#pragma unroll
    for (int h = 0; h < 8; ++h) { ce[cc][h] = s_qc[cb + h]; cx[cc][h] = s_qc[cb + 8 + h]; }
  }

  // ---- Phase 1: logits; reduce-scatter across the 16 c4 lanes
  {
    const int j0 = strip * 16;
#pragma unroll
    for (int jj = 0; jj < 16; ++jj) {
      const int j = j0 + jj;
      float4 E = e4[j * 16 + c4];
      float4 X = x4[j * 16 + c4];
      float acc[8];
#pragma unroll
      for (int h = 0; h < 8; ++h)
        acc[h] = E.x * ce[0][h] + E.y * ce[1][h] + E.z * ce[2][h] + E.w * ce[3][h]
               + X.x * cx[0][h] + X.y * cx[1][h] + X.z * cx[2][h] + X.w * cx[3][h];
      // level 1 (xor 8): keep 4, send 4
      float a4[4];
#pragma unroll
      for (int u = 0; u < 4; ++u) {
        float sent = (c4 & 8) ? acc[u] : acc[4 + u];
        float kept = (c4 & 8) ? acc[4 + u] : acc[u];
        a4[u] = kept + __shfl_xor(sent, 8, 64);
      }
      // level 2 (xor 4): keep 2
      float a2[2];
#pragma unroll
      for (int u = 0; u < 2; ++u) {
        float sent = (c4 & 4) ? a4[u] : a4[2 + u];
        float kept = (c4 & 4) ? a4[2 + u] : a4[u];
        a2[u] = kept + __shfl_xor(sent, 4, 64);
      }
      // level 3 (xor 2): keep 1
      float sent = (c4 & 2) ? a2[0] : a2[1];
      float kept = (c4 & 2) ? a2[1] : a2[0];
      float a1 = kept + __shfl_xor(sent, 2, 64);
      // level 4 (xor 1): full sum in both lanes of the pair
      a1 += __shfl_xor(a1, 1, 64);
      const int h = c4 >> 1;
      if (!(c4 & 1)) s_p[h * PSTR + j] = a1;
    }
  }
  __syncthreads();

  // ---- Phase 2: softmax per head, 64 lanes per head, normalize in place
  {
    const int n = t >> 6, l64 = t & 63;
    float m = -1e30f;
#pragma unroll
    for (int u = 0; u < 8; ++u) m = fmaxf(m, s_p[n * PSTR + l64 + u * 64]);
#pragma unroll
    for (int off = 32; off; off >>= 1) m = fmaxf(m, __shfl_xor(m, off, 64));
    float sum = 0;
#pragma unroll
    for (int u = 0; u < 8; ++u) {
      float p = __expf(s_p[n * PSTR + l64 + u * 64] - m);
      s_p[n * PSTR + l64 + u * 64] = p;
      sum += p;
    }
#pragma unroll
    for (int off = 32; off; off >>= 1) sum += __shfl_xor(sum, off, 64);
    const float inv = 1.0f / sum;
#pragma unroll
    for (int u = 0; u < 8; ++u) s_p[n * PSTR + l64 + u * 64] *= inv;
  }
  __syncthreads();

  // ---- Phase 3: ae[h,c] = sum_j p[h,j]e[j,c];  px[h,c] = sum_j p[h,j]x[j,c]
  {
    float ae[4][8], px[4][8];
#pragma unroll
    for (int cc = 0; cc < 4; ++cc)
#pragma unroll
      for (int h = 0; h < 8; ++h) { ae[cc][h] = 0.f; px[cc][h] = 0.f; }
    const int j0 = strip * 16;
#pragma unroll
    for (int jj = 0; jj < 16; ++jj) {
      const int j = j0 + jj;
      float4 E = e4[j * 16 + c4];
      float4 X = x4[j * 16 + c4];
      float pr[8];
#pragma unroll
      for (int h = 0; h < 8; ++h) pr[h] = s_p[h * PSTR + j];
#pragma unroll
      for (int h = 0; h < 8; ++h) {
        ae[0][h] += pr[h] * E.x; ae[1][h] += pr[h] * E.y;
        ae[2][h] += pr[h] * E.z; ae[3][h] += pr[h] * E.w;
        px[0][h] += pr[h] * X.x; px[1][h] += pr[h] * X.y;
        px[2][h] += pr[h] * X.z; px[3][h] += pr[h] * X.w;
      }
    }
    // reduce the 4 strips within this wave (xor 16, 32)
#pragma unroll
    for (int m = 16; m <= 32; m <<= 1) {
#pragma unroll
      for (int cc = 0; cc < 4; ++cc)
#pragma unroll
        for (int h = 0; h < 8; ++h) {
          ae[cc][h] += __shfl_xor(ae[cc][h], m, 64);
          px[cc][h] += __shfl_xor(px[cc][h], m, 64);
        }
    }
    const int wv = t >> 6;
    if ((t & 48) == 0) {   // lanes 0..15 of each wave
#pragma unroll
      for (int h = 0; h < 8; ++h) {
        *(float4*)&s_part[wv * 1024 + h * 64 + c4 * 4] =
            make_float4(ae[0][h], ae[1][h], ae[2][h], ae[3][h]);
        *(float4*)&s_part[wv * 1024 + 512 + h * 64 + c4 * 4] =
            make_float4(px[0][h], px[1][h], px[2][h], px[3][h]);
      }
    }
  }
  __syncthreads();

  // reduce the 8 wave partials
  {
    float va = 0, vp = 0;
#pragma unroll
    for (int w = 0; w < 8; ++w) {
      va += s_part[w * 1024 + t];
      vp += s_part[w * 1024 + 512 + t];
    }
    s_ae[t] = va; s_px[t] = vp;
  }
  __syncthreads();

  // ---- Epilogue: emb[nd] = sum_c ae[n,c]We[c,nd] + px[n,c]Wv[c,nd]
  {
    const int nd = t & 255, ch = t >> 8, hn = nd >> 5;
    float emb = 0;
    const int cb = ch * 32;
#pragma unroll 8
    for (int c = cb; c < cb + 32; ++c)
      emb += s_ae[hn * 64 + c] * We[c * 256 + nd] + s_px[hn * 64 + c] * Wv[c * 256 + nd];
    s_part[ch * 256 + nd] = emb;
  }
  __syncthreads();
  if (t < 256) s_emb[t] = s_part[t] + s_part[256 + t];
  __syncthreads();
  // out[o] = sum_m emb[m]*Wo[m,o] + bo[o]
  {
    const int o = t & 63, mc = t >> 6;
    float oo = 0;
#pragma unroll 8
    for (int m2 = mc * 32; m2 < mc * 32 + 32; ++m2) oo += s_emb[m2] * Wo[m2 * 64 + o];
    s_op[mc * 64 + o] = oo;
  }
  __syncthreads();
  if (t < 64) {
    float r = bo[t];
#pragma unroll
    for (int w = 0; w < 8; ++w) r += s_op[w * 64 + t];
    out[i * 64 + t] = r;
  }
}

extern "C" void kernel_launch(void* const* d_in, const int* in_sizes, int n_in,
                              void* d_out, int out_size, void* d_ws, size_t ws_size,
                              hipStream_t stream) {
  const float* x  = (const float*)d_in[0];
  const float* e  = (const float*)d_in[1];
  const float* Wq = (const float*)d_in[2];
  const float* Wk = (const float*)d_in[3];
  const float* Wv = (const float*)d_in[4];
  const float* We = (const float*)d_in[5];
  const float* Wo = (const float*)d_in[6];
  const float* bo = (const float*)d_in[7];
  float* out = (float*)d_out;

  hipLaunchKernelGGL(fused_kernel, dim3(512), dim3(512), 0, stream,
                     e, x, Wq, Wk, We, Wv, Wo, bo, out);
}

// Round 6
// 139.920 us; speedup vs baseline: 1.3037x; 1.3037x over previous
//
#include <hip/hip_runtime.h>

#define SCALE 0.17677669529663687f  // 1/sqrt(32)
#define PSTR 513                    // padded s_p row stride (bank spread)

// ---------------------------------------------------------------------------
// Single fused kernel: one block per query row i. 512 blocks x 512 thr.
//
// Prologue: q_s = (x[i]@Wq)*SCALE;
//   s_qc[c*16+h]   = sum_d q_s[h*32+d]*We[c*256+h*32+d]   (e-coef)
//   s_qc[c*16+8+h] = sum_d q_s[h*32+d]*Wk[c*256+h*32+d]   (x-coef)
// P1 (thread=j): logit[h][j] = sum_c e[i,j,c]*qce[c,h] + x[j,c]*qcx[c,h]
// P2: softmax over j per head; write transposed s_pt[j][h]
// P3 (lane=c, wave owns 64 j): ae[h,c]=sum_j p[h,j]e[j,c]; px likewise with x
// Epilogue: emb[nd] = sum_c ae[n,c]We[c,nd] + px[n,c]Wv[c,nd]; out = emb@Wo+bo
// ---------------------------------------------------------------------------
__global__ __launch_bounds__(512, 4) void fused_kernel(
    const float* __restrict__ e, const float* __restrict__ x,
    const float* __restrict__ Wq, const float* __restrict__ Wk,
    const float* __restrict__ We, const float* __restrict__ Wv,
    const float* __restrict__ Wo, const float* __restrict__ bo,
    float* __restrict__ out) {
  const int t = threadIdx.x, i = blockIdx.x;
  __shared__ float s_x[64];
  __shared__ __align__(16) float s_q[256];
  __shared__ __align__(16) float s_qc[1024];       //  4 KB coefs
  __shared__ __align__(16) float s_p[8 * PSTR];    // ~16 KB logits
  __shared__ __align__(16) float s_pt[512 * 8];    // 16 KB probs transposed [j][h]
  __shared__ __align__(16) float s_part[8 * 1024]; // 32 KB wave partials (ae|px)
  __shared__ float s_ae[512], s_px[512];
  __shared__ float s_emb[256];
  __shared__ float s_op[8 * 64];

  // ---- Prologue: coefficients
  if (t < 64) s_x[t] = x[i * 64 + t];
  __syncthreads();
  if (t < 256) {
    float a = 0;
#pragma unroll 8
    for (int c = 0; c < 64; ++c) a += s_x[c] * Wq[c * 256 + t];
    s_q[t] = a * SCALE;
  }
  __syncthreads();
  {
    const int c = t >> 3, h = t & 7;
    const float4* wer = (const float4*)(We + c * 256 + h * 32);
    const float4* wkr = (const float4*)(Wk + c * 256 + h * 32);
    const float4* qr = (const float4*)(s_q + h * 32);
    float se = 0, sk = 0;
#pragma unroll
    for (int u = 0; u < 8; ++u) {
      float4 w1 = wer[u], w2 = wkr[u], qv = qr[u];
      se += qv.x * w1.x + qv.y * w1.y + qv.z * w1.z + qv.w * w1.w;
      sk += qv.x * w2.x + qv.y * w2.y + qv.z * w2.z + qv.w * w2.w;
    }
    s_qc[c * 16 + h] = se;
    s_qc[c * 16 + 8 + h] = sk;
  }
  __syncthreads();

  // ---- Phase 1: one j per thread; coefs broadcast from LDS (uniform addrs)
  {
    const int j = t;
    const float4* erow = (const float4*)(e + (size_t)(i * 512 + j) * 64);
    const float4* xrow = (const float4*)(x + j * 64);
    float acc[8];
#pragma unroll
    for (int h = 0; h < 8; ++h) acc[h] = 0.f;
#pragma unroll 4
    for (int c4 = 0; c4 < 16; ++c4) {
      float4 E = erow[c4];
      float4 X = xrow[c4];
      const float* qc = s_qc + c4 * 64;   // 4 c's x 16 coefs, uniform address
#pragma unroll
      for (int h = 0; h < 8; ++h) {
        acc[h] += E.x * qc[h]      + E.y * qc[16 + h]
                + E.z * qc[32 + h] + E.w * qc[48 + h]
                + X.x * qc[8 + h]  + X.y * qc[24 + h]
                + X.z * qc[40 + h] + X.w * qc[56 + h];
      }
    }
#pragma unroll
    for (int h = 0; h < 8; ++h) s_p[h * PSTR + j] = acc[h];
  }
  __syncthreads();

  // ---- Phase 2: softmax per head (64 lanes/head); write transposed probs
  {
    const int n = t >> 6, l64 = t & 63;
    float m = -1e30f;
#pragma unroll
    for (int u = 0; u < 8; ++u) m = fmaxf(m, s_p[n * PSTR + l64 + u * 64]);
#pragma unroll
    for (int off = 32; off; off >>= 1) m = fmaxf(m, __shfl_xor(m, off, 64));
    float pv[8];
    float sum = 0;
#pragma unroll
    for (int u = 0; u < 8; ++u) {
      pv[u] = __expf(s_p[n * PSTR + l64 + u * 64] - m);
      sum += pv[u];
    }
#pragma unroll
    for (int off = 32; off; off >>= 1) sum += __shfl_xor(sum, off, 64);
    const float inv = 1.0f / sum;
#pragma unroll
    for (int u = 0; u < 8; ++u) s_pt[(l64 + u * 64) * 8 + n] = pv[u] * inv;
  }
  __syncthreads();

  // ---- Phase 3: lane=c, wave w owns j in [w*64, w*64+64)
  {
    const int lane = t & 63, w = t >> 6;
    float ae[8], px[8];
#pragma unroll
    for (int h = 0; h < 8; ++h) { ae[h] = 0.f; px[h] = 0.f; }
    const float* ep = e + (size_t)i * 32768 + (size_t)w * 4096 + lane;
    const float* xp = x + w * 4096 + lane;
#pragma unroll 4
    for (int jj = 0; jj < 64; ++jj) {
      const int j = w * 64 + jj;
      float ev = ep[jj * 64];          // coalesced 256B/wave
      float xv = xp[jj * 64];
      const float4* pt = (const float4*)(s_pt + j * 8);  // uniform -> broadcast
      float4 p0 = pt[0], p1 = pt[1];
      ae[0] += p0.x * ev; ae[1] += p0.y * ev; ae[2] += p0.z * ev; ae[3] += p0.w * ev;
      ae[4] += p1.x * ev; ae[5] += p1.y * ev; ae[6] += p1.z * ev; ae[7] += p1.w * ev;
      px[0] += p0.x * xv; px[1] += p0.y * xv; px[2] += p0.z * xv; px[3] += p0.w * xv;
      px[4] += p1.x * xv; px[5] += p1.y * xv; px[6] += p1.z * xv; px[7] += p1.w * xv;
    }
#pragma unroll
    for (int h = 0; h < 8; ++h) {
      s_part[w * 1024 + h * 64 + lane] = ae[h];
      s_part[w * 1024 + 512 + h * 64 + lane] = px[h];
    }
  }
  __syncthreads();

  // reduce the 8 wave partials
  {
    float va = 0, vp = 0;
#pragma unroll
    for (int w = 0; w < 8; ++w) {
      va += s_part[w * 1024 + t];
      vp += s_part[w * 1024 + 512 + t];
    }
    s_ae[t] = va; s_px[t] = vp;
  }
  __syncthreads();

  // ---- Epilogue: emb[nd] = sum_c ae[n,c]We[c,nd] + px[n,c]Wv[c,nd]
  {
    const int nd = t & 255, ch = t >> 8, hn = nd >> 5;
    float emb = 0;
    const int cb = ch * 32;
#pragma unroll 8
    for (int c = cb; c < cb + 32; ++c)
      emb += s_ae[hn * 64 + c] * We[c * 256 + nd] + s_px[hn * 64 + c] * Wv[c * 256 + nd];
    s_part[ch * 256 + nd] = emb;
  }
  __syncthreads();
  if (t < 256) s_emb[t] = s_part[t] + s_part[256 + t];
  __syncthreads();
  // out[o] = sum_m emb[m]*Wo[m,o] + bo[o]
  {
    const int o = t & 63, mc = t >> 6;
    float oo = 0;
#pragma unroll 8
    for (int m2 = mc * 32; m2 < mc * 32 + 32; ++m2) oo += s_emb[m2] * Wo[m2 * 64 + o];
    s_op[mc * 64 + o] = oo;
  }
  __syncthreads();
  if (t < 64) {
    float r = bo[t];
#pragma unroll
    for (int w = 0; w < 8; ++w) r += s_op[w * 64 + t];
    out[i * 64 + t] = r;
  }
}

extern "C" void kernel_launch(void* const* d_in, const int* in_sizes, int n_in,
                              void* d_out, int out_size, void* d_ws, size_t ws_size,
                              hipStream_t stream) {
  const float* x  = (const float*)d_in[0];
  const float* e  = (const float*)d_in[1];
  const float* Wq = (const float*)d_in[2];
  const float* Wk = (const float*)d_in[3];
  const float* Wv = (const float*)d_in[4];
  const float* We = (const float*)d_in[5];
  const float* Wo = (const float*)d_in[6];
  const float* bo = (const float*)d_in[7];
  float* out = (float*)d_out;

  hipLaunchKernelGGL(fused_kernel, dim3(512), dim3(512), 0, stream,
                     e, x, Wq, Wk, We, Wv, Wo, bo, out);
}